// Round 3
// baseline (111.405 us; speedup 1.0000x reference)
//
#include <hip/hip_runtime.h>
#include <hip/hip_cooperative_groups.h>

namespace cg = cooperative_groups;

// B=4, N=4096, D=64, depth=2 (fp32).
// out = MLP_dec( Y (Y^T Y) ), Y = rownorm(MLP_enc(x))   [associativity rewrite]
//
// R3: single cooperative kernel (256 blocks = 1/CU). Kills 2 launch/graph-node
// overheads (R1/R2 were invariant at 37us across very different kernel bodies
// => launch-bound, not pipe-bound) and the 8 MB y round-trip: the y tile
// lives in LDS across the two grid syncs.

constexpr int THREADS = 512;   // 8 waves; lane r = t&63 (row), q = t>>6 (col-eighth)

#define RFL(v) __builtin_amdgcn_readfirstlane(v)

__device__ __forceinline__ float readlane_f(float v, int lane) {
    return __int_as_float(__builtin_amdgcn_readlane(__float_as_int(v), lane));
}

__global__ __launch_bounds__(512) void fused_all(
        const float* __restrict__ x,
        const float* __restrict__ We,
        const float* __restrict__ Wd,
        float* __restrict__ out,
        float* ws) {
    __shared__ float sT[64][68];   // row tile; 68-stride = optimal 8-phase b128 reads
    __shared__ float sSq[64][8];

    const int t = threadIdx.x, r = t & 63;
    const int q = RFL(t >> 6);                 // wave-uniform -> SGPR (s_load weights)
    const int blk = blockIdx.x, bb = blk >> 6; // 64-row tile; batch
    const long base = (long)blk * 4096;

    float* partG = ws;                         // [256][4096]
    float* G     = ws + 256 * 4096;            // [4][4096]

    // ================= Phase A: enc MLP + rownorm + Gram partial =============
    const float4* xv = (const float4*)(x + base);
#pragma unroll
    for (int i = 0; i < 2; ++i) {
        const int e = t + i * 512;             // 0..1023 float4s
        *(float4*)&sT[e >> 4][(e & 15) * 4] = xv[e];
    }
    __syncthreads();

    float xr[64];
#pragma unroll
    for (int i = 0; i < 16; ++i) {
        const float4 v = *(const float4*)&sT[r][4 * i];
        xr[4*i] = v.x; xr[4*i+1] = v.y; xr[4*i+2] = v.z; xr[4*i+3] = v.w;
    }

    float h[8];
#pragma unroll
    for (int oo = 0; oo < 8; ++oo) {           // enc layer 1 (W via s_load)
        const float* wr = We + (q * 8 + oo) * 64;
        float acc = 0.f;
#pragma unroll
        for (int i = 0; i < 64; ++i) acc = fmaf(xr[i], wr[i], acc);
        h[oo] = fmaxf(acc, 0.f);
    }
    __syncthreads();
#pragma unroll
    for (int oo = 0; oo < 8; ++oo) sT[r][q * 8 + oo] = h[oo];
    __syncthreads();

#pragma unroll
    for (int i = 0; i < 16; ++i) {             // reload h1 row
        const float4 v = *(const float4*)&sT[r][4 * i];
        xr[4*i] = v.x; xr[4*i+1] = v.y; xr[4*i+2] = v.z; xr[4*i+3] = v.w;
    }
#pragma unroll
    for (int oo = 0; oo < 8; ++oo) {           // enc layer 2
        const float* wr = We + 4096 + (q * 8 + oo) * 64;
        float acc = 0.f;
#pragma unroll
        for (int i = 0; i < 64; ++i) acc = fmaf(xr[i], wr[i], acc);
        h[oo] = fmaxf(acc, 0.f);
    }

    float ss = 0.f;                            // row norm
#pragma unroll
    for (int j = 0; j < 8; ++j) ss += h[j] * h[j];
    sSq[r][q] = ss;
    __syncthreads();                           // (also: h1 reads all done)
    float tot = 0.f;
#pragma unroll
    for (int j = 0; j < 8; ++j) tot += sSq[r][j];
    const float scale = 1.f / (sqrtf(tot) + 1e-6f);
    float ys[8];
#pragma unroll
    for (int j = 0; j < 8; ++j) { ys[j] = h[j] * scale; sT[r][q * 8 + j] = ys[j]; }
    __syncthreads();                           // sT now holds the y tile (kept!)

    // Gram partial G[r][8q..]: col operand from LDS b32 (conflict-free),
    // broadcast operand via v_readlane from registers.
    float g[8] = {0.f,0.f,0.f,0.f,0.f,0.f,0.f,0.f};
#pragma unroll
    for (int row = 0; row < 64; ++row) {
        const float a = sT[row][r];
#pragma unroll
        for (int j = 0; j < 8; ++j)
            g[j] = fmaf(a, readlane_f(ys[j], row), g[j]);
    }
    float* pg = partG + (long)blk * 4096 + r * 64 + q * 8;
    *(float4*)pg       = make_float4(g[0], g[1], g[2], g[3]);
    *(float4*)(pg + 4) = make_float4(g[4], g[5], g[6], g[7]);

    cg::this_grid().sync();

    // ================= Phase B: reduce partG -> G[4][64][64] =================
    if (blk < 32) {
        const int e = blk * 512 + t;           // 0..16383
        const int b2 = e >> 12, idx = e & 4095;
        float s = 0.f;
#pragma unroll 8
        for (int j = 0; j < 64; ++j) s += partG[(long)(b2 * 64 + j) * 4096 + idx];
        G[e] = s;
    }

    cg::this_grid().sync();

    // ================= Phase C: z = y*G, dec MLP -> out ======================
    const float* Gb = G + bb * 4096;

    float yr[64];
#pragma unroll
    for (int i = 0; i < 16; ++i) {             // y row from preserved LDS tile
        const float4 v = *(const float4*)&sT[r][4 * i];
        yr[4*i] = v.x; yr[4*i+1] = v.y; yr[4*i+2] = v.z; yr[4*i+3] = v.w;
    }

    float z[8] = {0.f,0.f,0.f,0.f,0.f,0.f,0.f,0.f};
#pragma unroll
    for (int k = 0; k < 64; ++k) {             // G via uniform-address vector loads
        const float a = yr[k];
        const float4 g0 = *(const float4*)(Gb + k * 64 + q * 8);
        const float4 g1 = *(const float4*)(Gb + k * 64 + q * 8 + 4);
        z[0] = fmaf(a, g0.x, z[0]); z[1] = fmaf(a, g0.y, z[1]);
        z[2] = fmaf(a, g0.z, z[2]); z[3] = fmaf(a, g0.w, z[3]);
        z[4] = fmaf(a, g1.x, z[4]); z[5] = fmaf(a, g1.y, z[5]);
        z[6] = fmaf(a, g1.z, z[6]); z[7] = fmaf(a, g1.w, z[7]);
    }
    __syncthreads();                           // yr reads done
#pragma unroll
    for (int j = 0; j < 8; ++j) sT[r][q * 8 + j] = z[j];
    __syncthreads();

#pragma unroll
    for (int i = 0; i < 16; ++i) {             // z row
        const float4 v = *(const float4*)&sT[r][4 * i];
        yr[4*i] = v.x; yr[4*i+1] = v.y; yr[4*i+2] = v.z; yr[4*i+3] = v.w;
    }
#pragma unroll
    for (int oo = 0; oo < 8; ++oo) {           // dec layer 1
        const float* wr = Wd + (q * 8 + oo) * 64;
        float acc = 0.f;
#pragma unroll
        for (int i = 0; i < 64; ++i) acc = fmaf(yr[i], wr[i], acc);
        h[oo] = fmaxf(acc, 0.f);
    }
    __syncthreads();
#pragma unroll
    for (int oo = 0; oo < 8; ++oo) sT[r][q * 8 + oo] = h[oo];
    __syncthreads();

#pragma unroll
    for (int i = 0; i < 16; ++i) {             // h row
        const float4 v = *(const float4*)&sT[r][4 * i];
        yr[4*i] = v.x; yr[4*i+1] = v.y; yr[4*i+2] = v.z; yr[4*i+3] = v.w;
    }
    float o8[8];
#pragma unroll
    for (int oo = 0; oo < 8; ++oo) {           // dec layer 2
        const float* wr = Wd + 4096 + (q * 8 + oo) * 64;
        float acc = 0.f;
#pragma unroll
        for (int i = 0; i < 64; ++i) acc = fmaf(yr[i], wr[i], acc);
        o8[oo] = fmaxf(acc, 0.f);
    }
    float* po = out + base + r * 64 + q * 8;
    *(float4*)po       = make_float4(o8[0], o8[1], o8[2], o8[3]);
    *(float4*)(po + 4) = make_float4(o8[4], o8[5], o8[6], o8[7]);
}

extern "C" void kernel_launch(void* const* d_in, const int* in_sizes, int n_in,
                              void* d_out, int out_size, void* d_ws, size_t ws_size,
                              hipStream_t stream) {
    const float* x  = (const float*)d_in[0];   // [4,4096,64]
    const float* We = (const float*)d_in[1];   // [2,64,64]
    const float* Wd = (const float*)d_in[2];   // [2,64,64]
    float* outp = (float*)d_out;               // [4,4096,64] fp32
    float* wsp  = (float*)d_ws;                // needs ~4.3 MB (partG + G)

    void* args[] = {(void*)&x, (void*)&We, (void*)&Wd, (void*)&outp, (void*)&wsp};
    hipLaunchCooperativeKernel((void*)fused_all, dim3(256), dim3(THREADS),
                               args, 0, stream);
}